// Round 4
// baseline (1027.989 us; speedup 1.0000x reference)
//
#include <hip/hip_runtime.h>

// 3-layer tanh-RNN (B=512, T=2048, D=6, H=32, fp32), MI355X.
// One block / batch element, 3 waves / block, one wave per LAYER (pipelined,
// skew 1 phase per layer, barrier every KS=8 steps).
//
// R2 rocprof (bpermute version): 942us, VALUBusy 30%, DS-pipe-bound (~17 DS
// ops/step/wave across 6 waves/CU on the shared per-CU LDS pipe).
// Fix here: h-broadcast is wave-uniform -> v_readlane into SGPRs (own-SIMD
// VALU issue, no DS traffic); self-dot full-width with SGPR h operands
// (FMA's one allowed scalar operand). Cross-layer handoff stays in LDS:
// 4 uniform ds_read_b128 + 1 shfl_xor per step, issued FIRST so the ~120cy
// DS latency hides under the 32-readlane + 32-FMA self-dot block.

#define T_LEN 2048
#define D_IN  6
#define KS    8                // steps per phase (barrier period)
#define NPH   (T_LEN / KS)     // 256 phases

typedef float f4 __attribute__((ext_vector_type(4)));

// tanh(v) = 1 - 2/(e^{2v}+1); v_exp + v_rcp, ~1e-6 abs err, saturates right.
__device__ __forceinline__ float fast_tanh(float v) {
    float e = __expf(2.0f * v);
    return 1.0f - 2.0f / (e + 1.0f);
}

// wave-uniform broadcast: VALU v_readlane -> SGPR, no DS-pipe traffic.
__device__ __forceinline__ float rl(float v, int srclane) {
    return __int_as_float(__builtin_amdgcn_readlane(__float_as_int(v), srclane));
}

__global__ void __launch_bounds__(192) rnn3_pipe3(
    const float* __restrict__ x,     // [B, T, 6]
    const float* __restrict__ Wih0,  // [32, 6]
    const float* __restrict__ WihR,  // [2, 32, 32]
    const float* __restrict__ Whh,   // [3, 32, 32]
    const float* __restrict__ bih,   // [3, 32]
    const float* __restrict__ bhh,   // [3, 32]
    const float* __restrict__ fcw,   // [6, 32]
    const float* __restrict__ fcb,   // [6]
    float* __restrict__ out)         // [B, 6]
{
    const int b    = blockIdx.x;
    const int tid  = threadIdx.x;
    const int wid  = tid >> 6;      // 0,1,2 -> layer
    const int lane = tid & 63;
    const int j    = lane & 31;     // output index (lanes 32-63 duplicate 0-31)
    const int p    = lane >> 5;     // k-half for the cross-layer dot only

    __shared__ __align__(16) float ring1[2][KS][32];   // wave0 -> wave1
    __shared__ __align__(16) float ring2[2][KS][32];   // wave1 -> wave2

    // ---- per-wave weights ----
    float wh[32];                    // full recurrent row W_hh[wid][j][0..31]
    {
        const f4* q = (const f4*)(Whh + wid * 1024 + j * 32);
#pragma unroll
        for (int m = 0; m < 8; ++m) {
            f4 v = q[m];
#pragma unroll
            for (int i = 0; i < 4; ++i) wh[4 * m + i] = v[i];
        }
    }
    const float bs = bih[wid * 32 + j] + bhh[wid * 32 + j];

    float wi[16];                    // cross-layer row half (waves 1,2)
    float w0x[D_IN];                 // x row (wave 0)
    if (wid == 0) {
#pragma unroll
        for (int d = 0; d < D_IN; ++d) w0x[d] = Wih0[j * D_IN + d];
    } else {
        const f4* q = (const f4*)(WihR + (wid - 1) * 1024 + j * 32 + 16 * p);
#pragma unroll
        for (int m = 0; m < 4; ++m) {
            f4 v = q[m];
#pragma unroll
            for (int i = 0; i < 4; ++i) wi[4 * m + i] = v[i];
        }
    }

    // x staging (wave0): one dword per lane per phase (48 floats = KS*6)
    const float* xg = x + (size_t)b * (T_LEN * D_IN);
    float xcur = 0.0f, xnext = 0.0f;
    if (wid == 0 && lane < KS * D_IN) xcur = xg[lane];

    float h = 0.0f;                  // this wave's h(t-1)[j]; identical across halves

#pragma unroll 1
    for (int ph = 0; ph < NPH + 2; ++ph) {
        if (wid == 0) {
            if (ph < NPH) {
                if (ph + 1 < NPH && lane < KS * D_IN)
                    xnext = xg[(ph + 1) * (KS * D_IN) + lane];
                float (*r1)[32] = ring1[ph & 1];
#pragma unroll
                for (int s = 0; s < KS; ++s) {
                    // broadcast h(t-1) into SGPRs (own-SIMD VALU, no DS)
                    float hs[32];
#pragma unroll
                    for (int k = 0; k < 32; ++k) hs[k] = rl(h, k);
                    // x-projection (off the recurrent chain)
                    float xa = bs;
#pragma unroll
                    for (int d = 0; d < D_IN; ++d)
                        xa += rl(xcur, s * D_IN + d) * w0x[d];
                    float a0 = xa, a1 = 0.f, a2 = 0.f, a3 = 0.f;
#pragma unroll
                    for (int k = 0; k < 32; k += 4) {
                        a0 += hs[k    ] * wh[k    ];
                        a1 += hs[k + 1] * wh[k + 1];
                        a2 += hs[k + 2] * wh[k + 2];
                        a3 += hs[k + 3] * wh[k + 3];
                    }
                    h = fast_tanh((a0 + a1) + (a2 + a3));
                    if (lane < 32) r1[s][j] = h;
                }
                xcur = xnext;
            }
        } else if (wid == 1) {
            if (ph >= 1 && ph <= NPH) {
                float (*r1)[32] = ring1[(ph - 1) & 1];
                float (*r2)[32] = ring2[(ph - 1) & 1];
#pragma unroll
                for (int s = 0; s < KS; ++s) {
                    // 1) issue uniform ring reads FIRST (latency hides below)
                    const f4* rp = (const f4*)&r1[s][16 * p];
                    f4 v0 = rp[0], v1 = rp[1], v2 = rp[2], v3 = rp[3];
                    // 2) readlane broadcast block (independent of ds_reads)
                    float hs[32];
#pragma unroll
                    for (int k = 0; k < 32; ++k) hs[k] = rl(h, k);
                    // 3) self-dot FMA block
                    float a0 = bs, a1 = 0.f, a2 = 0.f, a3 = 0.f;
#pragma unroll
                    for (int k = 0; k < 32; k += 4) {
                        a0 += hs[k    ] * wh[k    ];
                        a1 += hs[k + 1] * wh[k + 1];
                        a2 += hs[k + 2] * wh[k + 2];
                        a3 += hs[k + 3] * wh[k + 3];
                    }
                    // 4) cross-layer dot (ds data has arrived by now)
                    float c0 = 0.f, c1 = 0.f, c2 = 0.f, c3 = 0.f;
#pragma unroll
                    for (int i = 0; i < 4; ++i) {
                        c0 += v0[i] * wi[i];
                        c1 += v1[i] * wi[4 + i];
                        c2 += v2[i] * wi[8 + i];
                        c3 += v3[i] * wi[12 + i];
                    }
                    float c = (c0 + c1) + (c2 + c3);
                    c += __shfl_xor(c, 32, 64);                 // combine k-halves
                    h = fast_tanh(((a0 + a1) + (a2 + a3)) + c);
                    if (lane < 32) r2[s][j] = h;
                }
            }
        } else {
            if (ph >= 2) {
                float (*r2)[32] = ring2[ph & 1];
#pragma unroll
                for (int s = 0; s < KS; ++s) {
                    const f4* rp = (const f4*)&r2[s][16 * p];
                    f4 v0 = rp[0], v1 = rp[1], v2 = rp[2], v3 = rp[3];
                    float hs[32];
#pragma unroll
                    for (int k = 0; k < 32; ++k) hs[k] = rl(h, k);
                    float a0 = bs, a1 = 0.f, a2 = 0.f, a3 = 0.f;
#pragma unroll
                    for (int k = 0; k < 32; k += 4) {
                        a0 += hs[k    ] * wh[k    ];
                        a1 += hs[k + 1] * wh[k + 1];
                        a2 += hs[k + 2] * wh[k + 2];
                        a3 += hs[k + 3] * wh[k + 3];
                    }
                    float c0 = 0.f, c1 = 0.f, c2 = 0.f, c3 = 0.f;
#pragma unroll
                    for (int i = 0; i < 4; ++i) {
                        c0 += v0[i] * wi[i];
                        c1 += v1[i] * wi[4 + i];
                        c2 += v2[i] * wi[8 + i];
                        c3 += v3[i] * wi[12 + i];
                    }
                    float c = (c0 + c1) + (c2 + c3);
                    c += __shfl_xor(c, 32, 64);
                    h = fast_tanh(((a0 + a1) + (a2 + a3)) + c);
                    // no ring write; h carried in register (h3 of last layer)
                }
            }
        }
        __syncthreads();
    }

    // ---- head (wave2 only): out[b] = h3(T-1) @ fc_w^T + fc_b, in-register ----
    if (wid == 2 && lane < D_IN) {
        float acc = fcb[lane];
        const float* fw = fcw + lane * 32;
#pragma unroll
        for (int k = 0; k < 32; ++k) acc += rl(h, k) * fw[k];
        out[b * D_IN + lane] = acc;
    }
}

extern "C" void kernel_launch(void* const* d_in, const int* in_sizes, int n_in,
                              void* d_out, int out_size, void* d_ws, size_t ws_size,
                              hipStream_t stream) {
    const float* x    = (const float*)d_in[0];
    const float* Wih0 = (const float*)d_in[1];
    const float* WihR = (const float*)d_in[2];
    const float* Whh  = (const float*)d_in[3];
    const float* bih  = (const float*)d_in[4];
    const float* bhh  = (const float*)d_in[5];
    const float* fcw  = (const float*)d_in[6];
    const float* fcb  = (const float*)d_in[7];
    float* outp = (float*)d_out;

    const int B = in_sizes[0] / (T_LEN * D_IN);  // 512
    rnn3_pipe3<<<B, 192, 0, stream>>>(x, Wih0, WihR, Whh, bih, bhh, fcw, fcb, outp);
}

// Round 5
// 474.445 us; speedup vs baseline: 2.1667x; 2.1667x over previous
//
#include <hip/hip_runtime.h>

// 3-layer tanh-RNN (B=512, T=2048, D=6, H=32, fp32), MI355X.
// One block / batch element, 3 waves / block, one wave per LAYER (pipelined,
// skew 1 phase/layer, barrier every KS=8 steps).
//
// Measured history: R2 (16x ds_bpermute/step) 942us; R4 (32x v_readlane/step)
// 1028us, VALUBusy 59.5%. Both ~1100 cy/step-slot => cross-lane ops cost ~8+cy
// each, dominating issue AND chain. R5 cuts cross-lane ops/step/wave from ~33
// to ~9: h broadcast via LDS round-trip (1 ds_write + 4 uniform ds_read_b128
// per dot, 2-addr broadcast = conflict-free), k-half combine via
// permlane32_swap (pure VALU, no DS), tanh via v_rcp (saves ~10-instr fdiv).

#define T_LEN 2048
#define D_IN  6
#define KS    8                 // steps per phase (barrier period)
#define NPH   (T_LEN / KS)      // 256 phases

typedef float f4 __attribute__((ext_vector_type(4)));
typedef unsigned int u2 __attribute__((ext_vector_type(2)));

#if defined(__has_builtin)
#  if __has_builtin(__builtin_amdgcn_permlane32_swap)
#    define HAVE_PLSWAP 1
#  endif
#endif

// c + c[lane^32]: with both operands = c, the two outputs of a 32-row swap
// hold {own-half, other-half} in every lane, so their sum is the combine.
__device__ __forceinline__ float xhalf_sum(float c) {
#ifdef HAVE_PLSWAP
    u2 r = __builtin_amdgcn_permlane32_swap(__float_as_uint(c), __float_as_uint(c),
                                            false, false);
    return __uint_as_float(r.x) + __uint_as_float(r.y);
#else
    return c + __shfl_xor(c, 32, 64);
#endif
}

// tanh(v) = 1 - 2/(e^{2v}+1); v_exp + raw v_rcp (~1e-7 rel), 5 VALU ops.
__device__ __forceinline__ float fast_tanh(float v) {
    float e = __expf(2.0f * v);
    float r = __builtin_amdgcn_rcpf(e + 1.0f);
    return __builtin_fmaf(-2.0f, r, 1.0f);
}

__device__ __forceinline__ float rl(float v, int srclane) {
    return __int_as_float(__builtin_amdgcn_readlane(__float_as_int(v), srclane));
}

__global__ void __launch_bounds__(192) rnn3_lds(
    const float* __restrict__ x,     // [B, T, 6]
    const float* __restrict__ Wih0,  // [32, 6]
    const float* __restrict__ WihR,  // [2, 32, 32]
    const float* __restrict__ Whh,   // [3, 32, 32]
    const float* __restrict__ bih,   // [3, 32]
    const float* __restrict__ bhh,   // [3, 32]
    const float* __restrict__ fcw,   // [6, 32]
    const float* __restrict__ fcb,   // [6]
    float* __restrict__ out)         // [B, 6]
{
    const int b    = blockIdx.x;
    const int tid  = threadIdx.x;
    const int wid  = tid >> 6;      // 0,1,2 -> layer
    const int lane = tid & 63;
    const int j    = lane & 31;     // output index (lanes 32-63 duplicate)
    const int p    = lane >> 5;     // k-half

    // ring[l][buf][s][lane]: wave l's h for each step of a phase. Serves BOTH
    // the wave's own next-step self-dot (same-wave in-order DS, no barrier)
    // and wave l+1's cross-layer input (one barrier later, other buffer).
    __shared__ __align__(16) float ring[3][2][KS][64];   // 12 KiB

    // ---- per-wave weights ----
    float wh[16];                    // W_hh[wid][j][16p + i]
    {
        const f4* q4 = (const f4*)(Whh + wid * 1024 + j * 32 + 16 * p);
        f4 q0 = q4[0], q1 = q4[1], q2 = q4[2], q3 = q4[3];
#pragma unroll
        for (int i = 0; i < 4; ++i) {
            wh[i] = q0[i]; wh[4 + i] = q1[i]; wh[8 + i] = q2[i]; wh[12 + i] = q3[i];
        }
    }
    const float bs = bih[wid * 32 + j] + bhh[wid * 32 + j];

    float wi[16];                    // cross-layer row half (waves 1,2)
    float w0x[D_IN];                 // x row (wave 0)
    if (wid == 0) {
#pragma unroll
        for (int d = 0; d < D_IN; ++d) w0x[d] = Wih0[j * D_IN + d];
    } else {
        const f4* q4 = (const f4*)(WihR + (wid - 1) * 1024 + j * 32 + 16 * p);
        f4 q0 = q4[0], q1 = q4[1], q2 = q4[2], q3 = q4[3];
#pragma unroll
        for (int i = 0; i < 4; ++i) {
            wi[i] = q0[i]; wi[4 + i] = q1[i]; wi[8 + i] = q2[i]; wi[12 + i] = q3[i];
        }
    }

    // h(-1) = 0: each wave zeroes the slot its q=0,s=0 self-read touches.
    ring[wid][1][KS - 1][lane] = 0.0f;   // own-wave in-order DS, no barrier

    // x staging (wave0): 48 floats per phase, one dword per lane.
    const float* xg = x + (size_t)b * (T_LEN * D_IN);
    float xcur = 0.0f, xnext = 0.0f;
    if (wid == 0 && lane < KS * D_IN) xcur = xg[lane];

#pragma unroll 1
    for (int ph = 0; ph < NPH + 2; ++ph) {
        const int q = ph - wid;              // this wave's sequence-phase
        if (q >= 0 && q < NPH) {
            const int qb = q & 1;
            float (*selfb)[64] = ring[wid][qb];
            float (*selfp)[64] = ring[wid][qb ^ 1];

            if (wid == 0) {
                // per-phase x projections (off the recurrent chain)
                float xa[KS];
#pragma unroll
                for (int s = 0; s < KS; ++s) {
                    float acc = bs;
#pragma unroll
                    for (int d = 0; d < D_IN; ++d)
                        acc += rl(xcur, s * D_IN + d) * w0x[d];
                    xa[s] = acc;
                }
                if (q + 1 < NPH && lane < KS * D_IN)
                    xnext = xg[(q + 1) * (KS * D_IN) + lane];

#pragma unroll
                for (int s = 0; s < KS; ++s) {
                    const float* hp = (s == 0) ? &selfp[KS - 1][16 * p]
                                               : &selfb[s - 1][16 * p];
                    const f4* h4 = (const f4*)hp;      // 2-addr broadcast reads
                    f4 h0 = h4[0], h1 = h4[1], h2 = h4[2], h3v = h4[3];
                    float a0 = 0.f, a1 = 0.f, a2 = 0.f, a3 = 0.f;
#pragma unroll
                    for (int i = 0; i < 4; ++i) {
                        a0 += h0[i] * wh[i];
                        a1 += h1[i] * wh[4 + i];
                        a2 += h2[i] * wh[8 + i];
                        a3 += h3v[i] * wh[12 + i];
                    }
                    float part = (a0 + a1) + (a2 + a3);
                    float h = fast_tanh(xhalf_sum(part) + xa[s]);
                    selfb[s][lane] = h;
                }
                xcur = xnext;
            } else {
                float (*srcb)[64] = ring[wid - 1][qb];   // barrier-old data
#pragma unroll
                for (int s = 0; s < KS; ++s) {
                    const f4* c4 = (const f4*)&srcb[s][16 * p];
                    f4 c0 = c4[0], c1 = c4[1], c2 = c4[2], c3 = c4[3];
                    const float* hp = (s == 0) ? &selfp[KS - 1][16 * p]
                                               : &selfb[s - 1][16 * p];
                    const f4* h4 = (const f4*)hp;
                    f4 h0 = h4[0], h1 = h4[1], h2 = h4[2], h3v = h4[3];
                    float a0 = 0.f, a1 = 0.f, a2 = 0.f, a3 = 0.f;
#pragma unroll
                    for (int i = 0; i < 4; ++i) {        // cross-layer dot
                        a0 += c0[i] * wi[i];
                        a1 += c1[i] * wi[4 + i];
                        a2 += c2[i] * wi[8 + i];
                        a3 += c3[i] * wi[12 + i];
                    }
#pragma unroll
                    for (int i = 0; i < 4; ++i) {        // self dot
                        a0 += h0[i] * wh[i];
                        a1 += h1[i] * wh[4 + i];
                        a2 += h2[i] * wh[8 + i];
                        a3 += h3v[i] * wh[12 + i];
                    }
                    float part = (a0 + a1) + (a2 + a3);
                    float h = fast_tanh(xhalf_sum(part) + bs);
                    selfb[s][lane] = h;
                }
            }
        }
        __syncthreads();
    }

    // ---- head (wave2): out[b] = h3(T-1) @ fc_w^T + fc_b ----
    if (wid == 2 && lane < D_IN) {
        const float* h3 = ring[2][(NPH - 1) & 1][KS - 1];  // own wave wrote it
        float acc = fcb[lane];
        const f4* fw = (const f4*)(fcw + lane * 32);
        const f4* hv = (const f4*)h3;
#pragma unroll
        for (int m = 0; m < 8; ++m) {
            f4 w4 = fw[m], hh = hv[m];
#pragma unroll
            for (int i = 0; i < 4; ++i) acc += hh[i] * w4[i];
        }
        out[b * D_IN + lane] = acc;
    }
}

extern "C" void kernel_launch(void* const* d_in, const int* in_sizes, int n_in,
                              void* d_out, int out_size, void* d_ws, size_t ws_size,
                              hipStream_t stream) {
    const float* x    = (const float*)d_in[0];
    const float* Wih0 = (const float*)d_in[1];
    const float* WihR = (const float*)d_in[2];
    const float* Whh  = (const float*)d_in[3];
    const float* bih  = (const float*)d_in[4];
    const float* bhh  = (const float*)d_in[5];
    const float* fcw  = (const float*)d_in[6];
    const float* fcb  = (const float*)d_in[7];
    float* outp = (float*)d_out;

    const int B = in_sizes[0] / (T_LEN * D_IN);  // 512
    rnn3_lds<<<B, 192, 0, stream>>>(x, Wih0, WihR, Whh, bih, bhh, fcw, fcb, outp);
}